// Round 3
// baseline (213.074 us; speedup 1.0000x reference)
//
#include <hip/hip_runtime.h>
#include <stdint.h>

typedef short bf16x8 __attribute__((ext_vector_type(8)));
typedef float f32x4  __attribute__((ext_vector_type(4)));
typedef float f32x16 __attribute__((ext_vector_type(16)));
typedef unsigned short u16;

#define B_  4
#define S_  2048
#define H_  768
#define NH_ 12
#define HD_ 64
#define NPROJ_N (3*H_)          // 2304

static __device__ __forceinline__ u16 f2bf(float f) {
    union { float f; unsigned int u; } x; x.f = f;
    return (u16)((x.u + 0x8000u) >> 16);
}
static __device__ __forceinline__ bf16x8 ld8(const u16* p) {
    return *(const bf16x8*)(const void*)p;
}
static __device__ __forceinline__ void st8(u16* p, bf16x8 v) {
    *(bf16x8*)(void*)p = v;
}
static __device__ __forceinline__ void async_ld16(const u16* g, const short* l) {
    __builtin_amdgcn_global_load_lds(
        (__attribute__((address_space(1))) void*)g,
        (__attribute__((address_space(3))) void*)l,
        16, 0, 0);
}
// pack 2 f32 -> u32 of 2 bf16 (lo = a, hi = b); no builtin on gfx950
static __device__ __forceinline__ unsigned cvtpk(float a, float b) {
    unsigned r;
    asm("v_cvt_pk_bf16_f32 %0, %1, %2" : "=v"(r) : "v"(a), "v"(b));
    return r;
}
// swap: a[32..63] <-> b[0..31]
static __device__ __forceinline__ void pl32swap(unsigned& a, unsigned& b) {
    asm("v_permlane32_swap_b32 %0, %1" : "+v"(a), "+v"(b));
}
static __device__ __forceinline__ bf16x8 mk8(unsigned a, unsigned b, unsigned c, unsigned d) {
    union { unsigned u[4]; bf16x8 v; } x;
    x.u[0] = a; x.u[1] = b; x.u[2] = c; x.u[3] = d;
    return x.v;
}

// ---------------- fused prep: hidden fp32->bf16 + W transpose + mask prescale -
// blocks [0,6144): hidden; [6144,7872): W tiles; [7872,7876): mask * log2e.
__global__ __launch_bounds__(256) void prep_kernel(const float* __restrict__ in,
                                                   u16* __restrict__ out,
                                                   const float* __restrict__ wq,
                                                   const float* __restrict__ wk,
                                                   const float* __restrict__ wv,
                                                   u16* __restrict__ wt,
                                                   const float* __restrict__ amask,
                                                   float* __restrict__ msc) {
    __shared__ float t[32][33];
    const int blk = blockIdx.x;
    const int tid = threadIdx.x;
    if (blk < 6144) {
        int i = (blk * 256 + tid) * 4;
        float4 v = *(const float4*)(in + i);
        ushort4 o;
        o.x = f2bf(v.x); o.y = f2bf(v.y); o.z = f2bf(v.z); o.w = f2bf(v.w);
        *(ushort4*)(out + i) = o;
    } else if (blk < 7872) {
        const int idx  = blk - 6144;              // 0..1727
        const int proj = idx / 576;
        const int rem  = idx % 576;
        const int bx = rem % 24, by = rem / 24;
        const float* w = (proj == 0) ? wq : (proj == 1) ? wk : wv;
        u16* o = wt + (size_t)proj * H_ * H_;
        const int tx = tid & 31, ty = tid >> 5;
        const int n0 = bx * 32, k0 = by * 32;
        #pragma unroll
        for (int i = 0; i < 4; i++)
            t[ty + i * 8][tx] = w[(size_t)(k0 + ty + i * 8) * H_ + n0 + tx];
        __syncthreads();
        #pragma unroll
        for (int i = 0; i < 4; i++)
            o[(size_t)(n0 + ty + i * 8) * H_ + k0 + tx] = f2bf(t[tx][ty + i * 8]);
    } else {
        // mask prescale: B*S = 8192 floats, 4 blocks x 256 thr x 8
        const int i = ((blk - 7872) * 256 + tid) * 8;
        float4 a0 = *(const float4*)(amask + i);
        float4 a1 = *(const float4*)(amask + i + 4);
        a0.x *= 1.44269504f; a0.y *= 1.44269504f; a0.z *= 1.44269504f; a0.w *= 1.44269504f;
        a1.x *= 1.44269504f; a1.y *= 1.44269504f; a1.z *= 1.44269504f; a1.w *= 1.44269504f;
        *(float4*)(msc + i)     = a0;
        *(float4*)(msc + i + 4) = a1;
    }
}

// ---------------- QKV projection GEMM: 128x128, dbuf, XCD-patch swizzle -------
__global__ __launch_bounds__(256) void qkv_gemm(const u16* __restrict__ A,
                                                const u16* __restrict__ Wt,
                                                const float* __restrict__ bq,
                                                const float* __restrict__ bk,
                                                const float* __restrict__ bv,
                                                u16* __restrict__ qo,
                                                u16* __restrict__ ko,
                                                u16* __restrict__ vto) {
    __shared__ alignas(16) short SMEM[4][128 * 64];   // 64 KB

    const int tid  = threadIdx.x;
    const int wave = tid >> 6;
    const int lane = tid & 63;
    const int quad = lane >> 4;
    const int l16  = lane & 15;
    const int wm   = wave & 1;
    const int wn   = wave >> 1;

    const int id  = blockIdx.x;
    const int xcd = id & 7;
    const int j   = id >> 3;
    const int mi  = j & 7;
    const int ni  = j >> 3;
    const int m0 = (xcd * 8 + mi) * 128;
    const int n0 = ni * 128;

    int stR[4], stC[4];
    #pragma unroll
    for (int jj = 0; jj < 4; jj++) {
        const int lc = wave * 256 + jj * 64 + lane;
        stR[jj] = lc >> 3;
        stC[jj] = ((lc & 7) ^ (stR[jj] & 7)) * 8;
    }
    const int fx0 = (quad ^ (l16 & 7)) * 8;
    const int fx1 = fx0 ^ 32;

    f32x4 acc[4][4];
    #pragma unroll
    for (int i = 0; i < 4; i++)
        #pragma unroll
        for (int jj = 0; jj < 4; jj++) acc[i][jj] = (f32x4)0.0f;

#define GSTAGE(kt_, buf_)                                                                     \
    do {                                                                                      \
        const int kk_ = (kt_) * 64;                                                           \
        _Pragma("unroll")                                                                     \
        for (int jj = 0; jj < 4; jj++) {                                                      \
            async_ld16(A  + (size_t)(m0 + stR[jj]) * H_ + kk_ + stC[jj],                      \
                       &SMEM[(buf_) * 2][(wave * 256 + jj * 64) * 8]);                        \
            async_ld16(Wt + (size_t)(n0 + stR[jj]) * H_ + kk_ + stC[jj],                      \
                       &SMEM[(buf_) * 2 + 1][(wave * 256 + jj * 64) * 8]);                    \
        }                                                                                     \
    } while (0)

    GSTAGE(0, 0);
    __syncthreads();

    for (int kt = 0; kt < 12; kt++) {
        const int cur = kt & 1;
        if (kt + 1 < 12) GSTAGE(kt + 1, cur ^ 1);
        const short* As = SMEM[cur * 2];
        const short* Bs = SMEM[cur * 2 + 1];
        #pragma unroll
        for (int ks = 0; ks < 2; ks++) {
            const int fx = ks ? fx1 : fx0;
            bf16x8 af[4], bfr[4];
            #pragma unroll
            for (int i = 0; i < 4; i++)
                af[i] = *(const bf16x8*)(const void*)&As[(wm * 64 + i * 16 + l16) * 64 + fx];
            #pragma unroll
            for (int jj = 0; jj < 4; jj++)
                bfr[jj] = *(const bf16x8*)(const void*)&Bs[(wn * 64 + jj * 16 + l16) * 64 + fx];
            #pragma unroll
            for (int i = 0; i < 4; i++)
                #pragma unroll
                for (int jj = 0; jj < 4; jj++)
                    acc[i][jj] = __builtin_amdgcn_mfma_f32_16x16x32_bf16(af[i], bfr[jj], acc[i][jj], 0, 0, 0);
        }
        __syncthreads();
    }
#undef GSTAGE

    const int proj  = n0 / H_;
    const int hbase = (n0 % H_) >> 6;
    const float* bias = (proj == 0) ? bq : (proj == 1) ? bk : bv;
    u16* Ct = (u16*)SMEM;

    #pragma unroll
    for (int nj = 0; nj < 4; nj++) {
        const int nl = wn * 64 + nj * 16 + l16;
        const float bv_ = bias[(n0 % H_) + nl];
        #pragma unroll
        for (int mi2 = 0; mi2 < 4; mi2++) {
            #pragma unroll
            for (int r = 0; r < 4; r++) {
                const int ml = wm * 64 + mi2 * 16 + quad * 4 + r;
                const u16 val = f2bf(acc[mi2][nj][r] + bv_);
                if (proj < 2)
                    Ct[ml * 128 + ((nl + (ml & 15) * 8) & 127)] = val;
                else
                    Ct[nl * 128 + ((ml + (nl & 15) * 8) & 127)] = val;
            }
        }
    }
    __syncthreads();

    if (proj < 2) {
        u16* dst0 = (proj == 0) ? qo : ko;
        const int c = tid & 7;
        #pragma unroll
        for (int jj = 0; jj < 8; jj++) {
            const int idx = jj * 32 + (tid >> 3);
            const int ml = idx >> 1, h2 = idx & 1;
            const int nbase = h2 * 64 + c * 8;
            bf16x8 v8 = *(const bf16x8*)(const void*)&Ct[ml * 128 + ((nbase + (ml & 15) * 8) & 127)];
            const int m = m0 + ml;
            const int b = m >> 11, s = m & 2047;
            st8(dst0 + ((size_t)(b * NH_ + hbase + h2) * S_ + s) * HD_ + c * 8, v8);
        }
    } else {
        const int b = m0 >> 11;
        #pragma unroll
        for (int jj = 0; jj < 8; jj++) {
            const int nl = (tid >> 3) + (jj & 3) * 32;
            const int c  = (tid & 7) + (jj >> 2) * 8;
            bf16x8 v8 = *(const bf16x8*)(const void*)&Ct[nl * 128 + ((c * 8 + (nl & 15) * 8) & 127)];
            const int h2 = nl >> 6, d = nl & 63;
            st8(vto + ((size_t)(b * NH_ + hbase + h2) * HD_ + d) * S_ + (m0 & 2047) + c * 8, v8);
        }
    }
}

// ---------------- flash attention: 32x32 swapped-QK, in-register P ------------
// 4 waves x 32 q-rows. Round-3 changes vs round-2:
//  - mask reads moved LDS -> VMEM (prescaled msc; L1-resident broadcasts),
//    issued BEFORE the K/V prefetch so softmax's vmcnt wait doesn't drain it.
//  - lsum computed by 4 extra MFMA vs a ones-B fragment (idle matrix pipe),
//    deleting the per-tile adds and the epilogue shuffle chain.
// LDS 32KB; grid 768 = 3 blocks/CU.
__global__ __launch_bounds__(256, 3) void attn_kernel(const u16* __restrict__ q,
                                                      const u16* __restrict__ k,
                                                      const u16* __restrict__ vt,
                                                      const float* __restrict__ msc,
                                                      float* __restrict__ out) {
    __shared__ alignas(16) short Ks[2][64 * 64];
    __shared__ alignas(16) short Vs[2][64 * 64];

    const int tid  = threadIdx.x;
    const int wave = tid >> 6;          // 0..3
    const int lane = tid & 63;
    const int l32  = lane & 31;
    const int h    = lane >> 5;

    const int bh = blockIdx.x;
    const int b  = bh / NH_;
    const int q0 = blockIdx.y * 128;
    const float C1 = 0.125f * 1.44269504f;

    // Q fragments (B-operand): lane holds q-row = l32, d = h*8 + j + 16*i
    const u16* qrow = q + ((size_t)bh * S_ + q0 + wave * 32 + l32) * HD_;
    bf16x8 qf[4];
    #pragma unroll
    for (int i = 0; i < 4; i++) qf[i] = ld8(qrow + i * 16 + h * 8);

    const u16* kbase = k  + (size_t)bh * S_ * HD_;
    const u16* vbase = vt + (size_t)bh * HD_ * S_;
    const float* mrow = msc + (size_t)b * S_ + h * 4;   // per-lane h-slice

    const int sRow = tid >> 3;                      // 0..31
    const int sCol = ((tid & 7) ^ (sRow & 7)) * 8;  // (row+32) keeps same row&7
    const int rx   = l32 & 7;

    // ones B-fragment for the lsum MFMA
    union { unsigned u[4]; bf16x8 v; } one_;
    one_.u[0] = 0x3F803F80u; one_.u[1] = 0x3F803F80u;
    one_.u[2] = 0x3F803F80u; one_.u[3] = 0x3F803F80u;
    const bf16x8 ones = one_.v;

    f32x16 lsacc = (f32x16)0.0f;
    f32x16 oacc0 = (f32x16)0.0f;
    f32x16 oacc1 = (f32x16)0.0f;

#define STAGE(kt_, buf_)                                                                           \
    do {                                                                                           \
        async_ld16(kbase + (size_t)(kt_) * 4096 + sRow * 64 + sCol,          &Ks[buf_][tid * 8]);  \
        async_ld16(kbase + (size_t)(kt_) * 4096 + (sRow + 32) * 64 + sCol,   &Ks[buf_][2048 + tid * 8]); \
        async_ld16(vbase + (size_t)sRow * S_ + (kt_) * 64 + sCol,            &Vs[buf_][tid * 8]);  \
        async_ld16(vbase + (size_t)(sRow + 32) * S_ + (kt_) * 64 + sCol,     &Vs[buf_][2048 + tid * 8]); \
    } while (0)

    STAGE(0, 0);
    __syncthreads();

    for (int kt = 0; kt < S_ / 64; kt++) {
        const int cur = kt & 1;

        // ---- mask loads FIRST (VMEM, wave-uniform -> broadcast, L1-hot) ----
        const float* mb = mrow + kt * 64;
        f32x4 mm0[4], mm1[4];
        #pragma unroll
        for (int c = 0; c < 4; c++) {
            mm0[c] = *(const f32x4*)(mb + c * 8);
            mm1[c] = *(const f32x4*)(mb + 32 + c * 8);
        }

        if (kt + 1 < S_ / 64) STAGE(kt + 1, cur ^ 1);
        const short* Kc = Ks[cur];
        const short* Vc = Vs[cur];

        // ---- swapped QK^T: s[k][q] = mfma(A=K, B=Q); lane col = q ----
        f32x16 s0 = (f32x16)0.0f;   // k-block 0..31
        f32x16 s1 = (f32x16)0.0f;   // k-block 32..63
        __builtin_amdgcn_s_setprio(1);
        #pragma unroll
        for (int i = 0; i < 4; i++) {
            const int ch = ((h + 2 * i) ^ rx) * 8;
            bf16x8 kf0 = *(const bf16x8*)(const void*)&Kc[l32 * 64 + ch];
            bf16x8 kf1 = *(const bf16x8*)(const void*)&Kc[(l32 + 32) * 64 + ch];
            s0 = __builtin_amdgcn_mfma_f32_32x32x16_bf16(kf0, qf[i], s0, 0, 0, 0);
            s1 = __builtin_amdgcn_mfma_f32_32x32x16_bf16(kf1, qf[i], s1, 0, 0, 0);
        }
        __builtin_amdgcn_s_setprio(0);

        // ---- softmax exp + in-register bf16 pack ----
        // reg r of s{0,1}: k = (r&3) + 8*(r>>2) + 4*h (+32 for s1)
        unsigned w0[8], w1[8];
        #pragma unroll
        for (int c = 0; c < 4; c++) {
            const float p00 = __builtin_amdgcn_exp2f(__builtin_fmaf(s0[4*c+0], C1, mm0[c][0]));
            const float p01 = __builtin_amdgcn_exp2f(__builtin_fmaf(s0[4*c+1], C1, mm0[c][1]));
            const float p02 = __builtin_amdgcn_exp2f(__builtin_fmaf(s0[4*c+2], C1, mm0[c][2]));
            const float p03 = __builtin_amdgcn_exp2f(__builtin_fmaf(s0[4*c+3], C1, mm0[c][3]));
            const float p10 = __builtin_amdgcn_exp2f(__builtin_fmaf(s1[4*c+0], C1, mm1[c][0]));
            const float p11 = __builtin_amdgcn_exp2f(__builtin_fmaf(s1[4*c+1], C1, mm1[c][1]));
            const float p12 = __builtin_amdgcn_exp2f(__builtin_fmaf(s1[4*c+2], C1, mm1[c][2]));
            const float p13 = __builtin_amdgcn_exp2f(__builtin_fmaf(s1[4*c+3], C1, mm1[c][3]));
            w0[2*c]   = cvtpk(p00, p01);
            w0[2*c+1] = cvtpk(p02, p03);
            w1[2*c]   = cvtpk(p10, p11);
            w1[2*c+1] = cvtpk(p12, p13);
        }

        // ---- permlane repack: A-frags for PV (k = 16t + 8h + j) ----
        bf16x8 pa[4];
        #pragma unroll
        for (int t = 0; t < 2; t++) {
            {
                unsigned a = w0[4*t+0], bb = w0[4*t+2];
                pl32swap(a, bb);
                unsigned c2 = w0[4*t+1], dd = w0[4*t+3];
                pl32swap(c2, dd);
                pa[t] = mk8(a, c2, bb, dd);
            }
            {
                unsigned a = w1[4*t+0], bb = w1[4*t+2];
                pl32swap(a, bb);
                unsigned c2 = w1[4*t+1], dd = w1[4*t+3];
                pl32swap(c2, dd);
                pa[2 + t] = mk8(a, c2, bb, dd);
            }
        }

        // ---- PV + lsum: O = mfma(P, V); lsum = mfma(P, ones) ----
        __builtin_amdgcn_s_setprio(1);
        #pragma unroll
        for (int t = 0; t < 4; t++) {
            const int ch = ((h + 2 * t) ^ rx) * 8;
            bf16x8 vf0 = *(const bf16x8*)(const void*)&Vc[l32 * 64 + ch];
            bf16x8 vf1 = *(const bf16x8*)(const void*)&Vc[(l32 + 32) * 64 + ch];
            oacc0 = __builtin_amdgcn_mfma_f32_32x32x16_bf16(pa[t], vf0, oacc0, 0, 0, 0);
            oacc1 = __builtin_amdgcn_mfma_f32_32x32x16_bf16(pa[t], vf1, oacc1, 0, 0, 0);
            lsacc = __builtin_amdgcn_mfma_f32_32x32x16_bf16(pa[t], ones, lsacc, 0, 0, 0);
        }
        __builtin_amdgcn_s_setprio(0);
        __syncthreads();
    }
#undef STAGE

    // ---- epilogue: lsum already in C/D row layout -> no shuffles ----
    const int hh = bh % NH_;
    #pragma unroll
    for (int r = 0; r < 16; r++) {
        const int qq = (r & 3) + 8 * (r >> 2) + 4 * h;
        const float linv = 1.0f / lsacc[r];
        const int s = q0 + wave * 32 + qq;
        float* orow = out + ((size_t)b * S_ + s) * H_ + hh * 64 + l32;
        orow[0]  = oacc0[r] * linv;
        orow[32] = oacc1[r] * linv;
    }
}

extern "C" void kernel_launch(void* const* d_in, const int* in_sizes, int n_in,
                              void* d_out, int out_size, void* d_ws, size_t ws_size,
                              hipStream_t stream) {
    const float* hidden = (const float*)d_in[0];
    const float* amask  = (const float*)d_in[1];
    const float* Wq     = (const float*)d_in[2];
    const float* bq     = (const float*)d_in[3];
    const float* Wk     = (const float*)d_in[4];
    const float* bk     = (const float*)d_in[5];
    const float* Wv     = (const float*)d_in[6];
    const float* bv     = (const float*)d_in[7];
    float* out = (float*)d_out;

    char* ws = (char*)d_ws;
    const size_t sz_hidden = (size_t)B_ * S_ * H_ * 2;
    const size_t sz_wt     = (size_t)NPROJ_N * H_ * 2;
    const size_t sz_qkv    = (size_t)B_ * S_ * H_ * 2;

    u16* hid_bf = (u16*)(ws);
    u16* wt     = (u16*)(ws + sz_hidden);
    u16* qbuf   = (u16*)(ws + sz_hidden + sz_wt);
    u16* kbuf   = (u16*)(ws + sz_hidden + sz_wt + sz_qkv);
    u16* vtbuf  = (u16*)(ws + sz_hidden + sz_wt + 2 * sz_qkv);
    float* msc  = (float*)(ws + sz_hidden + sz_wt + 3 * sz_qkv);

    prep_kernel<<<dim3(6144 + 1728 + 4), dim3(256), 0, stream>>>(
        hidden, hid_bf, Wq, Wk, Wv, wt, amask, msc);
    qkv_gemm<<<dim3(1152), dim3(256), 0, stream>>>(
        hid_bf, wt, bq, bk, bv, qbuf, kbuf, vtbuf);
    attn_kernel<<<dim3(B_ * NH_, S_ / 128), dim3(256), 0, stream>>>(
        qbuf, kbuf, vtbuf, msc, out);
}

// Round 4
// 204.208 us; speedup vs baseline: 1.0434x; 1.0434x over previous
//
#include <hip/hip_runtime.h>
#include <stdint.h>

typedef short bf16x8 __attribute__((ext_vector_type(8)));
typedef float f32x4  __attribute__((ext_vector_type(4)));
typedef float f32x16 __attribute__((ext_vector_type(16)));
typedef unsigned short u16;

#define B_  4
#define S_  2048
#define H_  768
#define NH_ 12
#define HD_ 64
#define NPROJ_N (3*H_)          // 2304

static __device__ __forceinline__ u16 f2bf(float f) {
    union { float f; unsigned int u; } x; x.f = f;
    return (u16)((x.u + 0x8000u) >> 16);
}
static __device__ __forceinline__ bf16x8 ld8(const u16* p) {
    return *(const bf16x8*)(const void*)p;
}
static __device__ __forceinline__ void st8(u16* p, bf16x8 v) {
    *(bf16x8*)(void*)p = v;
}
static __device__ __forceinline__ void async_ld16(const u16* g, const short* l) {
    __builtin_amdgcn_global_load_lds(
        (__attribute__((address_space(1))) void*)g,
        (__attribute__((address_space(3))) void*)l,
        16, 0, 0);
}
// pack 2 f32 -> u32 of 2 bf16 (lo = a, hi = b); no builtin on gfx950
static __device__ __forceinline__ unsigned cvtpk(float a, float b) {
    unsigned r;
    asm("v_cvt_pk_bf16_f32 %0, %1, %2" : "=v"(r) : "v"(a), "v"(b));
    return r;
}
// swap: a[32..63] <-> b[0..31]
static __device__ __forceinline__ void pl32swap(unsigned& a, unsigned& b) {
    asm("v_permlane32_swap_b32 %0, %1" : "+v"(a), "+v"(b));
}
static __device__ __forceinline__ bf16x8 mk8(unsigned a, unsigned b, unsigned c, unsigned d) {
    union { unsigned u[4]; bf16x8 v; } x;
    x.u[0] = a; x.u[1] = b; x.u[2] = c; x.u[3] = d;
    return x.v;
}

// ---------------- fused prep: hidden fp32->bf16 + W transpose + mask prescale -
__global__ __launch_bounds__(256) void prep_kernel(const float* __restrict__ in,
                                                   u16* __restrict__ out,
                                                   const float* __restrict__ wq,
                                                   const float* __restrict__ wk,
                                                   const float* __restrict__ wv,
                                                   u16* __restrict__ wt,
                                                   const float* __restrict__ amask,
                                                   float* __restrict__ msc) {
    __shared__ float t[32][33];
    const int blk = blockIdx.x;
    const int tid = threadIdx.x;
    if (blk < 6144) {
        int i = (blk * 256 + tid) * 4;
        float4 v = *(const float4*)(in + i);
        ushort4 o;
        o.x = f2bf(v.x); o.y = f2bf(v.y); o.z = f2bf(v.z); o.w = f2bf(v.w);
        *(ushort4*)(out + i) = o;
    } else if (blk < 7872) {
        const int idx  = blk - 6144;              // 0..1727
        const int proj = idx / 576;
        const int rem  = idx % 576;
        const int bx = rem % 24, by = rem / 24;
        const float* w = (proj == 0) ? wq : (proj == 1) ? wk : wv;
        u16* o = wt + (size_t)proj * H_ * H_;
        const int tx = tid & 31, ty = tid >> 5;
        const int n0 = bx * 32, k0 = by * 32;
        #pragma unroll
        for (int i = 0; i < 4; i++)
            t[ty + i * 8][tx] = w[(size_t)(k0 + ty + i * 8) * H_ + n0 + tx];
        __syncthreads();
        #pragma unroll
        for (int i = 0; i < 4; i++)
            o[(size_t)(n0 + ty + i * 8) * H_ + k0 + tx] = f2bf(t[tx][ty + i * 8]);
    } else {
        // mask prescale: B*S = 8192 floats, 4 blocks x 256 thr x 8
        const int i = ((blk - 7872) * 256 + tid) * 8;
        float4 a0 = *(const float4*)(amask + i);
        float4 a1 = *(const float4*)(amask + i + 4);
        a0.x *= 1.44269504f; a0.y *= 1.44269504f; a0.z *= 1.44269504f; a0.w *= 1.44269504f;
        a1.x *= 1.44269504f; a1.y *= 1.44269504f; a1.z *= 1.44269504f; a1.w *= 1.44269504f;
        *(float4*)(msc + i)     = a0;
        *(float4*)(msc + i + 4) = a1;
    }
}

// ---------------- QKV projection GEMM: 128x128, dbuf, XCD-patch swizzle -------
__global__ __launch_bounds__(256) void qkv_gemm(const u16* __restrict__ A,
                                                const u16* __restrict__ Wt,
                                                const float* __restrict__ bq,
                                                const float* __restrict__ bk,
                                                const float* __restrict__ bv,
                                                u16* __restrict__ qo,
                                                u16* __restrict__ ko,
                                                u16* __restrict__ vto) {
    __shared__ alignas(16) short SMEM[4][128 * 64];   // 64 KB

    const int tid  = threadIdx.x;
    const int wave = tid >> 6;
    const int lane = tid & 63;
    const int quad = lane >> 4;
    const int l16  = lane & 15;
    const int wm   = wave & 1;
    const int wn   = wave >> 1;

    const int id  = blockIdx.x;
    const int xcd = id & 7;
    const int j   = id >> 3;
    const int mi  = j & 7;
    const int ni  = j >> 3;
    const int m0 = (xcd * 8 + mi) * 128;
    const int n0 = ni * 128;

    int stR[4], stC[4];
    #pragma unroll
    for (int jj = 0; jj < 4; jj++) {
        const int lc = wave * 256 + jj * 64 + lane;
        stR[jj] = lc >> 3;
        stC[jj] = ((lc & 7) ^ (stR[jj] & 7)) * 8;
    }
    const int fx0 = (quad ^ (l16 & 7)) * 8;
    const int fx1 = fx0 ^ 32;

    f32x4 acc[4][4];
    #pragma unroll
    for (int i = 0; i < 4; i++)
        #pragma unroll
        for (int jj = 0; jj < 4; jj++) acc[i][jj] = (f32x4)0.0f;

#define GSTAGE(kt_, buf_)                                                                     \
    do {                                                                                      \
        const int kk_ = (kt_) * 64;                                                           \
        _Pragma("unroll")                                                                     \
        for (int jj = 0; jj < 4; jj++) {                                                      \
            async_ld16(A  + (size_t)(m0 + stR[jj]) * H_ + kk_ + stC[jj],                      \
                       &SMEM[(buf_) * 2][(wave * 256 + jj * 64) * 8]);                        \
            async_ld16(Wt + (size_t)(n0 + stR[jj]) * H_ + kk_ + stC[jj],                      \
                       &SMEM[(buf_) * 2 + 1][(wave * 256 + jj * 64) * 8]);                    \
        }                                                                                     \
    } while (0)

    GSTAGE(0, 0);
    __syncthreads();

    for (int kt = 0; kt < 12; kt++) {
        const int cur = kt & 1;
        if (kt + 1 < 12) GSTAGE(kt + 1, cur ^ 1);
        const short* As = SMEM[cur * 2];
        const short* Bs = SMEM[cur * 2 + 1];
        #pragma unroll
        for (int ks = 0; ks < 2; ks++) {
            const int fx = ks ? fx1 : fx0;
            bf16x8 af[4], bfr[4];
            #pragma unroll
            for (int i = 0; i < 4; i++)
                af[i] = *(const bf16x8*)(const void*)&As[(wm * 64 + i * 16 + l16) * 64 + fx];
            #pragma unroll
            for (int jj = 0; jj < 4; jj++)
                bfr[jj] = *(const bf16x8*)(const void*)&Bs[(wn * 64 + jj * 16 + l16) * 64 + fx];
            #pragma unroll
            for (int i = 0; i < 4; i++)
                #pragma unroll
                for (int jj = 0; jj < 4; jj++)
                    acc[i][jj] = __builtin_amdgcn_mfma_f32_16x16x32_bf16(af[i], bfr[jj], acc[i][jj], 0, 0, 0);
        }
        __syncthreads();
    }
#undef GSTAGE

    const int proj  = n0 / H_;
    const int hbase = (n0 % H_) >> 6;
    const float* bias = (proj == 0) ? bq : (proj == 1) ? bk : bv;
    u16* Ct = (u16*)SMEM;

    #pragma unroll
    for (int nj = 0; nj < 4; nj++) {
        const int nl = wn * 64 + nj * 16 + l16;
        const float bv_ = bias[(n0 % H_) + nl];
        #pragma unroll
        for (int mi2 = 0; mi2 < 4; mi2++) {
            #pragma unroll
            for (int r = 0; r < 4; r++) {
                const int ml = wm * 64 + mi2 * 16 + quad * 4 + r;
                const u16 val = f2bf(acc[mi2][nj][r] + bv_);
                if (proj < 2)
                    Ct[ml * 128 + ((nl + (ml & 15) * 8) & 127)] = val;
                else
                    Ct[nl * 128 + ((ml + (nl & 15) * 8) & 127)] = val;
            }
        }
    }
    __syncthreads();

    if (proj < 2) {
        u16* dst0 = (proj == 0) ? qo : ko;
        const int c = tid & 7;
        #pragma unroll
        for (int jj = 0; jj < 8; jj++) {
            const int idx = jj * 32 + (tid >> 3);
            const int ml = idx >> 1, h2 = idx & 1;
            const int nbase = h2 * 64 + c * 8;
            bf16x8 v8 = *(const bf16x8*)(const void*)&Ct[ml * 128 + ((nbase + (ml & 15) * 8) & 127)];
            const int m = m0 + ml;
            const int b = m >> 11, s = m & 2047;
            st8(dst0 + ((size_t)(b * NH_ + hbase + h2) * S_ + s) * HD_ + c * 8, v8);
        }
    } else {
        const int b = m0 >> 11;
        #pragma unroll
        for (int jj = 0; jj < 8; jj++) {
            const int nl = (tid >> 3) + (jj & 3) * 32;
            const int c  = (tid & 7) + (jj >> 2) * 8;
            bf16x8 v8 = *(const bf16x8*)(const void*)&Ct[nl * 128 + ((c * 8 + (nl & 15) * 8) & 127)];
            const int h2 = nl >> 6, d = nl & 63;
            st8(vto + ((size_t)(b * NH_ + hbase + h2) * HD_ + d) * S_ + (m0 & 2047) + c * 8, v8);
        }
    }
}

// ---------------- flash attention: (q-group 64) x (k-half 32) wave split ------
// 4 waves = 2 qg x 2 kh. Each wave reads only its k-half of K/V (8 b128 vs 16),
// each fragment feeds 2 q-blocks. Cross-wave O-partial reduction once at end,
// reusing K/V LDS. Mask via LDS broadcast (round-2 proven); lsum via VALU.
__global__ __launch_bounds__(256, 3) void attn_kernel(const u16* __restrict__ q,
                                                      const u16* __restrict__ k,
                                                      const u16* __restrict__ vt,
                                                      const float* __restrict__ msc,
                                                      float* __restrict__ out) {
    __shared__ alignas(16) short Ks[2][4096];   // 16 KB (reused: qg=0 O-partials)
    __shared__ alignas(16) short Vs[2][4096];   // 16 KB (reused: qg=1 O-partials)
    __shared__ alignas(16) float Ms[S_];        // 8 KB prescaled mask (reused: lsum xchg)

    const int tid  = threadIdx.x;
    const int wave = tid >> 6;          // 0..3
    const int lane = tid & 63;
    const int l32  = lane & 31;
    const int h    = lane >> 5;
    const int kh   = wave & 1;          // k-half 0/1
    const int qg   = wave >> 1;         // q-group 0/1 (64 rows each)

    const int bh = blockIdx.x;
    const int b  = bh / NH_;
    const int q0 = blockIdx.y * 128;
    const float C1 = 0.125f * 1.44269504f;

    // mask preload (already prescaled by log2e in prep)
    {
        const float* mrow = msc + (size_t)b * S_;
        float4 a0 = *(const float4*)(mrow + tid * 8);
        float4 a1 = *(const float4*)(mrow + tid * 8 + 4);
        *(float4*)(Ms + tid * 8)     = a0;
        *(float4*)(Ms + tid * 8 + 4) = a1;
    }

    // Q fragments (B-operand), 2 q-blocks of 32: q = q0 + qg*64 + qb*32 + l32
    bf16x8 qf[2][4];
    #pragma unroll
    for (int qb = 0; qb < 2; qb++) {
        const u16* qrow = q + ((size_t)bh * S_ + q0 + qg * 64 + qb * 32 + l32) * HD_;
        #pragma unroll
        for (int i = 0; i < 4; i++) qf[qb][i] = ld8(qrow + i * 16 + h * 8);
    }

    const u16* kbase = k  + (size_t)bh * S_ * HD_;
    const u16* vbase = vt + (size_t)bh * HD_ * S_;

    const int sRow = tid >> 3;                      // 0..31
    const int sCol = ((tid & 7) ^ (sRow & 7)) * 8;  // (row+32) keeps same row&7
    const int rx   = l32 & 7;

    float ls0 = 0.f, ls1 = 0.f;                     // per-lane lsum partials (q = l32 col)
    f32x16 oacc[2][2];                              // [qb][d-half], partial over own k-half
    #pragma unroll
    for (int qb = 0; qb < 2; qb++)
        #pragma unroll
        for (int dh = 0; dh < 2; dh++) oacc[qb][dh] = (f32x16)0.0f;

#define STAGE(kt_, buf_)                                                                           \
    do {                                                                                           \
        async_ld16(kbase + (size_t)(kt_) * 4096 + sRow * 64 + sCol,          &Ks[buf_][tid * 8]);  \
        async_ld16(kbase + (size_t)(kt_) * 4096 + (sRow + 32) * 64 + sCol,   &Ks[buf_][2048 + tid * 8]); \
        async_ld16(vbase + (size_t)sRow * S_ + (kt_) * 64 + sCol,            &Vs[buf_][tid * 8]);  \
        async_ld16(vbase + (size_t)(sRow + 32) * S_ + (kt_) * 64 + sCol,     &Vs[buf_][2048 + tid * 8]); \
    } while (0)

    STAGE(0, 0);
    __syncthreads();   // covers Ms writes + STAGE(0)

    for (int kt = 0; kt < S_ / 64; kt++) {
        const int cur = kt & 1;
        if (kt + 1 < S_ / 64) STAGE(kt + 1, cur ^ 1);
        const short* Kc = Ks[cur];
        const short* Vc = Vs[cur];

        // ---- swapped QK^T on own k-half: s[qb][k-local][q] = mfma(K, Q) ----
        f32x16 s0 = (f32x16)0.0f;   // q-block 0
        f32x16 s1 = (f32x16)0.0f;   // q-block 1
        __builtin_amdgcn_s_setprio(1);
        #pragma unroll
        for (int i = 0; i < 4; i++) {
            bf16x8 kf = *(const bf16x8*)(const void*)&Kc[kh * 2048 + l32 * 64 + (((h + 2 * i) ^ rx) * 8)];
            s0 = __builtin_amdgcn_mfma_f32_32x32x16_bf16(kf, qf[0][i], s0, 0, 0, 0);
            s1 = __builtin_amdgcn_mfma_f32_32x32x16_bf16(kf, qf[1][i], s1, 0, 0, 0);
        }
        __builtin_amdgcn_s_setprio(0);

        // ---- softmax exp + pack; reg r: k-local = (r&3) + 8*(r>>2) + 4h ----
        unsigned w0[8], w1[8];
        #pragma unroll
        for (int c = 0; c < 4; c++) {
            const f32x4 mm = *(const f32x4*)&Ms[kt * 64 + kh * 32 + c * 8 + h * 4];
            const float p00 = __builtin_amdgcn_exp2f(__builtin_fmaf(s0[4*c+0], C1, mm[0]));
            const float p01 = __builtin_amdgcn_exp2f(__builtin_fmaf(s0[4*c+1], C1, mm[1]));
            const float p02 = __builtin_amdgcn_exp2f(__builtin_fmaf(s0[4*c+2], C1, mm[2]));
            const float p03 = __builtin_amdgcn_exp2f(__builtin_fmaf(s0[4*c+3], C1, mm[3]));
            const float p10 = __builtin_amdgcn_exp2f(__builtin_fmaf(s1[4*c+0], C1, mm[0]));
            const float p11 = __builtin_amdgcn_exp2f(__builtin_fmaf(s1[4*c+1], C1, mm[1]));
            const float p12 = __builtin_amdgcn_exp2f(__builtin_fmaf(s1[4*c+2], C1, mm[2]));
            const float p13 = __builtin_amdgcn_exp2f(__builtin_fmaf(s1[4*c+3], C1, mm[3]));
            w0[2*c]   = cvtpk(p00, p01);
            w0[2*c+1] = cvtpk(p02, p03);
            w1[2*c]   = cvtpk(p10, p11);
            w1[2*c+1] = cvtpk(p12, p13);
            ls0 += (p00 + p01) + (p02 + p03);
            ls1 += (p10 + p11) + (p12 + p13);
        }

        // ---- permlane repack: A-frags, k-local = 16t + 8h + j ----
        bf16x8 pa0[2], pa1[2];
        #pragma unroll
        for (int t = 0; t < 2; t++) {
            {
                unsigned a = w0[4*t+0], bb = w0[4*t+2];
                pl32swap(a, bb);
                unsigned c2 = w0[4*t+1], dd = w0[4*t+3];
                pl32swap(c2, dd);
                pa0[t] = mk8(a, c2, bb, dd);
            }
            {
                unsigned a = w1[4*t+0], bb = w1[4*t+2];
                pl32swap(a, bb);
                unsigned c2 = w1[4*t+1], dd = w1[4*t+3];
                pl32swap(c2, dd);
                pa1[t] = mk8(a, c2, bb, dd);
            }
        }

        // ---- PV on own k-half: each V fragment feeds both q-blocks ----
        __builtin_amdgcn_s_setprio(1);
        #pragma unroll
        for (int t = 0; t < 2; t++) {
            #pragma unroll
            for (int dh = 0; dh < 2; dh++) {
                bf16x8 vf = *(const bf16x8*)(const void*)&Vc[dh * 2048 + l32 * 64 + (((kh * 4 + 2 * t + h) ^ rx) * 8)];
                oacc[0][dh] = __builtin_amdgcn_mfma_f32_32x32x16_bf16(pa0[t], vf, oacc[0][dh], 0, 0, 0);
                oacc[1][dh] = __builtin_amdgcn_mfma_f32_32x32x16_bf16(pa1[t], vf, oacc[1][dh], 0, 0, 0);
            }
        }
        __builtin_amdgcn_s_setprio(0);
        __syncthreads();
    }
#undef STAGE

    // ---- epilogue: cross-(k-half) reduction via LDS, then normalize+store ----
    ls0 += __shfl_xor(ls0, 32);
    ls1 += __shfl_xor(ls1, 32);

    float* R = qg ? (float*)Vs : (float*)Ks;   // 4096 floats per q-group

    if (kh == 1) {
        #pragma unroll
        for (int qb = 0; qb < 2; qb++)
            #pragma unroll
            for (int dh = 0; dh < 2; dh++)
                #pragma unroll
                for (int r = 0; r < 16; r++) {
                    const int qrow = (r & 3) + 8 * (r >> 2) + 4 * h;
                    R[(qb * 32 + qrow) * 64 + dh * 32 + l32] = oacc[qb][dh][r];
                }
        if (lane < 32) {
            Ms[qg * 64 + l32]      = ls0;
            Ms[qg * 64 + 32 + l32] = ls1;
        }
    }
    __syncthreads();

    if (kh == 0) {
        const float li0 = 1.0f / (ls0 + Ms[qg * 64 + l32]);
        const float li1 = 1.0f / (ls1 + Ms[qg * 64 + 32 + l32]);
        const int hh = bh % NH_;
        #pragma unroll
        for (int r = 0; r < 16; r++) {
            const int qrow = (r & 3) + 8 * (r >> 2) + 4 * h;
            const float lv0 = __shfl(li0, qrow);
            const float lv1 = __shfl(li1, qrow);
            #pragma unroll
            for (int dh = 0; dh < 2; dh++) {
                const int d = dh * 32 + l32;
                const int s0r = q0 + qg * 64 + qrow;
                out[((size_t)b * S_ + s0r) * H_ + hh * 64 + d] =
                    (oacc[0][dh][r] + R[qrow * 64 + d]) * lv0;
                out[((size_t)b * S_ + s0r + 32) * H_ + hh * 64 + d] =
                    (oacc[1][dh][r] + R[(32 + qrow) * 64 + d]) * lv1;
            }
        }
    }
}

extern "C" void kernel_launch(void* const* d_in, const int* in_sizes, int n_in,
                              void* d_out, int out_size, void* d_ws, size_t ws_size,
                              hipStream_t stream) {
    const float* hidden = (const float*)d_in[0];
    const float* amask  = (const float*)d_in[1];
    const float* Wq     = (const float*)d_in[2];
    const float* bq     = (const float*)d_in[3];
    const float* Wk     = (const float*)d_in[4];
    const float* bk     = (const float*)d_in[5];
    const float* Wv     = (const float*)d_in[6];
    const float* bv     = (const float*)d_in[7];
    float* out = (float*)d_out;

    char* ws = (char*)d_ws;
    const size_t sz_hidden = (size_t)B_ * S_ * H_ * 2;
    const size_t sz_wt     = (size_t)NPROJ_N * H_ * 2;
    const size_t sz_qkv    = (size_t)B_ * S_ * H_ * 2;

    u16* hid_bf = (u16*)(ws);
    u16* wt     = (u16*)(ws + sz_hidden);
    u16* qbuf   = (u16*)(ws + sz_hidden + sz_wt);
    u16* kbuf   = (u16*)(ws + sz_hidden + sz_wt + sz_qkv);
    u16* vtbuf  = (u16*)(ws + sz_hidden + sz_wt + 2 * sz_qkv);
    float* msc  = (float*)(ws + sz_hidden + sz_wt + 3 * sz_qkv);

    prep_kernel<<<dim3(6144 + 1728 + 4), dim3(256), 0, stream>>>(
        hidden, hid_bf, Wq, Wk, Wv, wt, amask, msc);
    qkv_gemm<<<dim3(1152), dim3(256), 0, stream>>>(
        hid_bf, wt, bq, bk, bv, qbuf, kbuf, vtbuf);
    attn_kernel<<<dim3(B_ * NH_, S_ / 128), dim3(256), 0, stream>>>(
        qbuf, kbuf, vtbuf, msc, out);
}